// Round 5
// baseline (348.219 us; speedup 1.0000x reference)
//
#include <hip/hip_runtime.h>
#include <hip/hip_fp16.h>

#define B_   8
#define CIN  256
#define T_   4096
#define TP   4097    // padded T (row 0 = zeros, row t+1 = x[t])
#define CO   256
#define O4   1024
#define NN   32768   // B_*T_
#define NCH  128     // chunks along T
#define CL   32      // chunk length

// ws layout (float offsets)
#define OFF_XHI  0           // ushort [8][4097][256]
#define OFF_XLO  4195328
#define OFF_WHI  8390656     // ushort [1024][512]
#define OFF_WLO  8652800
// scan state (decoupled lookback): 2048 tiles x 32 channels
#define OFF_AGGA 21497856    // float [2048][32]
#define OFF_AGGB 21563392
#define OFF_PREF 21628928
#define OFF_FLAG 21694464    // int [2048]

typedef __attribute__((ext_vector_type(8))) short short8;
typedef __attribute__((ext_vector_type(4))) float floatx4;

__device__ __forceinline__ float fsig(float x)  { return 1.0f / (1.0f + __expf(-x)); }
__device__ __forceinline__ float ftanh(float x) { return 2.0f / (1.0f + __expf(-2.0f * x)) - 1.0f; }

__device__ __forceinline__ unsigned short bf16_rne(float v) {
    unsigned u = __float_as_uint(v);
    unsigned r = (u + 0x7fffu + ((u >> 16) & 1u)) >> 16;
    return (unsigned short)r;
}
__device__ __forceinline__ void split_bf16(float v, unsigned short& hi, unsigned short& lo) {
    hi = bf16_rne(v);
    float hf = __uint_as_float(((unsigned)hi) << 16);
    lo = bf16_rne(v - hf);
}

// async 16B/lane global->LDS DMA; lds base must be wave-uniform (dest = base + lane*16)
__device__ __forceinline__ void glds16(const unsigned short* g, unsigned short* l) {
    __builtin_amdgcn_global_load_lds(
        (const __attribute__((address_space(1))) unsigned*)g,
        (__attribute__((address_space(3))) unsigned*)l, 16, 0, 0);
}

// agent-scope (device) atomics: coherent across XCD L2s
__device__ __forceinline__ float aloadf(const float* p) {
    return __hip_atomic_load(p, __ATOMIC_RELAXED, __HIP_MEMORY_SCOPE_AGENT);
}
__device__ __forceinline__ void astoref(float* p, float v) {
    __hip_atomic_store(p, v, __ATOMIC_RELAXED, __HIP_MEMORY_SCOPE_AGENT);
}

// merged converts: bid<2048 -> W repack/split; 2048<=bid<4096 -> X transpose/split;
// bid>=4096 -> zero lookback flags (must precede gemm every iteration).
__global__ void convert_kernel(const float* __restrict__ W,
                               const float* __restrict__ x,
                               unsigned short* __restrict__ Whi,
                               unsigned short* __restrict__ Wlo,
                               unsigned short* __restrict__ Xhi,
                               unsigned short* __restrict__ Xlo,
                               int* __restrict__ flags) {
    __shared__ float tile[64][69];      // 69 mod 32 = 5 -> conflict-free both phases
    const int bid = blockIdx.x;
    const int tid = threadIdx.x;
    if (bid >= 4096) {                  // flag reset: 8 blocks x 256 = 2048 ints
        int i = (bid - 4096) * 256 + tid;
        if (i < 2048) flags[i] = 0;
        return;
    }
    if (bid < 2048) {
        int e = bid * 256 + tid;        // 1024*512 elements
        int r = e >> 9, k = e & 511;
        int g = r & 3, c = r >> 2;
        int j = k >> 8, i = k & 255;
        float v = W[((size_t)((g << 8) + c)) * 512 + i * 2 + j];
        unsigned short hi, lo;
        split_bf16(v, hi, lo);
        Whi[e] = hi;
        Wlo[e] = lo;
        return;
    }
    const int b2 = bid - 2048;
    const int t0 = (b2 & 63) * 64;
    const int c0 = ((b2 >> 6) & 3) * 64;
    const int b  = b2 >> 8;

    {   // read: float4 along t, 16 rows per pass
        int j4 = (tid & 15) * 4, r16 = tid >> 4;
#pragma unroll
        for (int p = 0; p < 4; p++) {
            int i = p * 16 + r16;
            float4 v = *(const float4*)&x[((size_t)(b * 256 + c0 + i)) * T_ + t0 + j4];
            tile[i][j4] = v.x; tile[i][j4 + 1] = v.y;
            tile[i][j4 + 2] = v.z; tile[i][j4 + 3] = v.w;
        }
    }
    if (t0 == 0 && tid < 64) {   // zero pad row (x[-1] = 0)
        size_t z = (size_t)b * TP * 256 + c0 + tid;
        Xhi[z] = 0; Xlo[z] = 0;
    }
    __syncthreads();
    {   // write: 4 consecutive channels per thread, packed uint2 (8B) stores
        const int cslot = tid & 15, trow = tid >> 4;
#pragma unroll
        for (int p = 0; p < 4; p++) {
            int t = p * 16 + trow;
            unsigned hi0, hi1, lo0, lo1;
            {
                unsigned short h, l;
                split_bf16(tile[cslot * 4 + 0][t], h, l);
                hi0 = h; lo0 = l;
                split_bf16(tile[cslot * 4 + 1][t], h, l);
                hi0 |= ((unsigned)h) << 16; lo0 |= ((unsigned)l) << 16;
                split_bf16(tile[cslot * 4 + 2][t], h, l);
                hi1 = h; lo1 = l;
                split_bf16(tile[cslot * 4 + 3][t], h, l);
                hi1 |= ((unsigned)h) << 16; lo1 |= ((unsigned)l) << 16;
            }
            size_t idx = ((size_t)b * TP + t0 + t + 1) * 256 + c0 + cslot * 4;
            uint2 ph; ph.x = hi0; ph.y = hi1;
            uint2 pl; pl.x = lo0; pl.y = lo1;
            *(uint2*)&Xhi[idx] = ph;
            *(uint2*)&Xlo[idx] = pl;
        }
    }
}

// Fully-fused: GEMM (split-bf16, 3 products, 128x128 tile, BK=32, round-4
// schedule) + activations + chunk scan + DECOUPLED LOOKBACK over t-tiles +
// replay + direct write of h = o*c to out[b][c][t]. Eliminates fw/izw/ow
// round trip and the scan2/scan3 kernels.
// Grid map (round 4, FETCH=33MB proven): bid = tt*64 + r_blk*8 + b — strictly
// tt-monotone in bid per (b,r) stream => lookback waits only on lower-bid
// blocks (dispatch-order forward progress, rocPRIM-style).
// Publish protocol: payload relaxed agent stores -> __threadfence() (wave-wide
// drain + L2 writeback) -> flag store; reader: flag acquire-load then payload.
__launch_bounds__(512, 4)
__global__ void gemm_mfma_kernel(const unsigned short* __restrict__ Xhi,
                                 const unsigned short* __restrict__ Xlo,
                                 const unsigned short* __restrict__ Whi,
                                 const unsigned short* __restrict__ Wlo,
                                 const float* __restrict__ bias,
                                 float* __restrict__ out,
                                 float* __restrict__ aggA,
                                 float* __restrict__ aggB,
                                 float* __restrict__ pref,
                                 int* __restrict__ flags)
{
    __shared__ unsigned short smem_us[32768];   // 64 KiB

    const int tid  = threadIdx.x;
    const int wave = tid >> 6, lane = tid & 63;
    const int q = lane >> 4, mr = lane & 15;
    const int wm = wave >> 2, wn = wave & 3;     // 2 x 4 wave grid (M x N)

    // grid: 2048 = 8 xcd x (32 t-tiles x 8 r, r fastest); xcd == b
    const int bid   = blockIdx.x;
    const int xcd   = bid & 7;
    const int idx   = bid >> 3;                  // 0..255
    const int n_blk = xcd * 32 + (idx >> 3);     // 0..255
    const int r_blk = idx & 7;                   // 0..7
    const int r0 = r_blk * 128;
    const int n0 = n_blk * 128;
    const int bb = n0 >> 12;
    const int t0 = n0 & (T_ - 1);
    const int tt = t0 >> 7;                      // t-tile index 0..31

    // staging: wave w stages rows w*16..w*16+15 of each plane; 1 DMA per plane
    const int lrow = lane >> 2;            // 0..15
    const int lcol = (lane & 3) * 8;       // ushort offset in row
    const size_t wAoff = (size_t)(r0 + wave * 16 + lrow) * 512 + lcol;
    const unsigned short* pWh = Whi + wAoff;
    const unsigned short* pWl = Wlo + wAoff;
    const size_t xBoff = ((size_t)bb * TP + t0 + wave * 16 + lrow) * 256 + lcol;
    const unsigned short* pXh = Xhi + xBoff;
    const unsigned short* pXl = Xlo + xBoff;

    // fragment read bases (ushort offsets within one plane)
    const int aoffb = (wm * 64 + mr) * 32 + q * 8;
    const int boffb = (wn * 32 + mr) * 32 + q * 8;
    const int wst = wave * 512;                  // wave staging offset in plane

    floatx4 acc[4][2];
#pragma unroll
    for (int v = 0; v < 4; v++)
#pragma unroll
        for (int u = 0; u < 2; u++) acc[v][u] = (floatx4){0.f, 0.f, 0.f, 0.f};

    // prologue: stage K-step 0 into buffer 0, order AH,BH,BL,AL (oldest first)
    glds16(pWh, smem_us + wst);
    glds16(pXh, smem_us + 8192 + wst);
    glds16(pXl, smem_us + 12288 + wst);
    glds16(pWl, smem_us + 4096 + wst);
    asm volatile("s_waitcnt vmcnt(2)" ::: "memory");   // AH,BH landed; BL,AL in flight
    __builtin_amdgcn_s_barrier();
    __builtin_amdgcn_sched_barrier(0);

#pragma unroll 2
    for (int i = 0; i < 16; ++i) {
        const int cur = i & 1, nxt = cur ^ 1;
        const unsigned kk = (unsigned)(((i + 1) & 15) * 32);   // wrap keeps counts uniform
        const unsigned short* AHc = smem_us + cur * 16384;
        const unsigned short* ALc = AHc + 4096;
        const unsigned short* BHc = AHc + 8192;
        const unsigned short* BLc = AHc + 12288;
        unsigned short* dAH = smem_us + nxt * 16384 + wst;
        unsigned short* dAL = dAH + 4096;
        unsigned short* dBH = dAH + 8192;
        unsigned short* dBL = dAH + 12288;

        short8 ah[4], bh[2];

        // ---------- P0: hi*hi ----------
#pragma unroll
        for (int v = 0; v < 4; ++v) ah[v] = *(const short8*)(AHc + aoffb + v * 512);
#pragma unroll
        for (int u = 0; u < 2; ++u) bh[u] = *(const short8*)(BHc + boffb + u * 512);
        glds16(pWh + kk, dAH);
        glds16(pXh + kk, dBH);
        asm volatile("s_waitcnt lgkmcnt(0)" ::: "memory");
        __builtin_amdgcn_sched_barrier(0);
        __builtin_amdgcn_s_setprio(1);
#pragma unroll
        for (int v = 0; v < 4; ++v)
#pragma unroll
            for (int u = 0; u < 2; ++u)
                acc[v][u] = __builtin_amdgcn_mfma_f32_16x16x32_bf16(ah[v], bh[u], acc[v][u], 0, 0, 0);
        __builtin_amdgcn_s_setprio(0);
        asm volatile("s_waitcnt vmcnt(3)" ::: "memory");   // BL[cur] landed
        __builtin_amdgcn_s_barrier();
        __builtin_amdgcn_sched_barrier(0);

        // ---------- P1: hi*lo ----------
        {
            short8 bl[2];
#pragma unroll
            for (int u = 0; u < 2; ++u) bl[u] = *(const short8*)(BLc + boffb + u * 512);
            glds16(pXl + kk, dBL);
            asm volatile("s_waitcnt lgkmcnt(0)" ::: "memory");
            __builtin_amdgcn_sched_barrier(0);
            __builtin_amdgcn_s_setprio(1);
#pragma unroll
            for (int v = 0; v < 4; ++v)
#pragma unroll
                for (int u = 0; u < 2; ++u)
                    acc[v][u] = __builtin_amdgcn_mfma_f32_16x16x32_bf16(ah[v], bl[u], acc[v][u], 0, 0, 0);
            __builtin_amdgcn_s_setprio(0);
        }
        asm volatile("s_waitcnt vmcnt(3)" ::: "memory");   // AL[cur] landed
        __builtin_amdgcn_s_barrier();
        __builtin_amdgcn_sched_barrier(0);

        // ---------- P2: lo*hi ----------
        {
            short8 al[4];
#pragma unroll
            for (int v = 0; v < 4; ++v) al[v] = *(const short8*)(ALc + aoffb + v * 512);
            glds16(pWl + kk, dAL);
            asm volatile("s_waitcnt lgkmcnt(0)" ::: "memory");
            __builtin_amdgcn_sched_barrier(0);
            __builtin_amdgcn_s_setprio(1);
#pragma unroll
            for (int v = 0; v < 4; ++v)
#pragma unroll
                for (int u = 0; u < 2; ++u)
                    acc[v][u] = __builtin_amdgcn_mfma_f32_16x16x32_bf16(al[v], bh[u], acc[v][u], 0, 0, 0);
            __builtin_amdgcn_s_setprio(0);
        }
        asm volatile("s_waitcnt vmcnt(2)" ::: "memory");   // AH,BH[nxt] landed
        __builtin_amdgcn_s_barrier();
        __builtin_amdgcn_sched_barrier(0);
    }

    // ---------- fused epilogue: activations + scan + lookback + replay ----------
    asm volatile("s_waitcnt vmcnt(0)" ::: "memory");   // drain wrap-staging junk DMAs
    __syncthreads();                     // LDS reused below
    __half* epf = (__half*)smem_us;      // [128][36] f16, 72B rows
    __half* epz = epf + 128 * 36;
    __half* epo = epz + 128 * 36;        // ends at byte 27648
    float* chA_l  = (float*)(smem_us + 13824);   // [4][32] chunk aggregates
    float* chB_l  = chA_l + 128;
    float* csst_l = chB_l + 128;                 // [32] tile start carry
    const int ch_base = r0 >> 2;         // 32 channels per block

#pragma unroll
    for (int v = 0; v < 4; ++v) {
        const int cl = wm * 16 + v * 4 + q;          // local channel 0..31
        const int ch = ch_base + cl;
        const float bz  = bias[ch];
        const float bf_ = bias[256 + ch];
        const float bo  = bias[512 + ch];
        const float bi  = bias[768 + ch];
#pragma unroll
        for (int u = 0; u < 2; ++u) {
            const int t_l = wn * 32 + u * 16 + mr;   // local t 0..127
            float zv = ftanh(acc[v][u][0] + bz);
            float fv = fsig(acc[v][u][1] + bf_);
            float ov = fsig(acc[v][u][2] + bo);
            float iv = fsig(acc[v][u][3] + bi);
            const int off = t_l * 36 + cl;
            epf[off] = __float2half(fv);             // f16 rounding as before
            epz[off] = __float2half(iv * zv);
            epo[off] = __float2half(ov);
        }
    }
    __syncthreads();

    // chunk summaries (4 chunks x 32 channels)
    if (tid < 128) {
        const int c = tid & 31, chunk = tid >> 5;
        float A = 1.0f, Bv = 0.0f;
        const int base = (chunk * 32) * 36 + c;
#pragma unroll 4
        for (int j = 0; j < 32; ++j) {
            float f  = __half2float(epf[base + j * 36]);
            float iz = __half2float(epz[base + j * 36]);
            Bv = fmaf(f, Bv, iz);
            A *= f;
        }
        chA_l[chunk * 32 + c] = A;
        chB_l[chunk * 32 + c] = Bv;
    }
    __syncthreads();

    // tile aggregate + publish + decoupled lookback (wave 0, lanes 0..31)
    if (tid < 32) {
        const int c = tid;
        float At = 1.0f, Bt = 0.0f;
#pragma unroll
        for (int k = 0; k < 4; ++k) {
            Bt = fmaf(chA_l[k * 32 + c], Bt, chB_l[k * 32 + c]);
            At *= chA_l[k * 32 + c];
        }
        const int fi  = (bb * 8 + r_blk) * 32 + tt;
        const int fi0 = fi - tt;
        astoref(&aggA[(size_t)fi * 32 + c], At);
        astoref(&aggB[(size_t)fi * 32 + c], Bt);
        __threadfence();
        if (c == 0) __hip_atomic_store(&flags[fi], 1, __ATOMIC_RELAXED, __HIP_MEMORY_SCOPE_AGENT);

        float cs = 0.0f, coef = 1.0f;
        for (int j = tt - 1; j >= 0; --j) {
            int fl;
            for (;;) {
                fl = __hip_atomic_load(&flags[fi0 + j], __ATOMIC_ACQUIRE, __HIP_MEMORY_SCOPE_AGENT);
                if (fl != 0) break;
                __builtin_amdgcn_s_sleep(8);
            }
            if (fl == 2) {   // inclusive prefix available: done
                cs = fmaf(coef, aloadf(&pref[(size_t)(fi0 + j) * 32 + c]), cs);
                break;
            }
            cs = fmaf(coef, aloadf(&aggB[(size_t)(fi0 + j) * 32 + c]), cs);
            coef *= aloadf(&aggA[(size_t)(fi0 + j) * 32 + c]);
        }
        float myP = fmaf(At, cs, Bt);
        astoref(&pref[(size_t)fi * 32 + c], myP);
        __threadfence();
        if (c == 0) __hip_atomic_store(&flags[fi], 2, __ATOMIC_RELAXED, __HIP_MEMORY_SCOPE_AGENT);
        csst_l[c] = cs;
    }
    __syncthreads();

    // replay recurrence from carry, write h = o*c straight to out[b][c][t]
    if (tid < 128) {
        const int c = tid & 31, chunk = tid >> 5;
        float cs = csst_l[c];
        for (int k = 0; k < chunk; ++k)
            cs = fmaf(chA_l[k * 32 + c], cs, chB_l[k * 32 + c]);
        float* op = out + ((size_t)(bb * CO + ch_base + c)) * T_ + t0 + chunk * 32;
#pragma unroll
        for (int g = 0; g < 8; ++g) {
            float4 h4;
#pragma unroll
            for (int j = 0; j < 4; ++j) {
                const int t_l = chunk * 32 + g * 4 + j;
                float f  = __half2float(epf[t_l * 36 + c]);
                float iz = __half2float(epz[t_l * 36 + c]);
                float o  = __half2float(epo[t_l * 36 + c]);
                cs = fmaf(f, cs, iz);
                (&h4.x)[j] = o * cs;
            }
            *(float4*)(op + g * 4) = h4;
        }
    }
}

extern "C" void kernel_launch(void* const* d_in, const int* in_sizes, int n_in,
                              void* d_out, int out_size, void* d_ws, size_t ws_size,
                              hipStream_t stream) {
    const float* x    = (const float*)d_in[0];
    const float* W    = (const float*)d_in[1];
    const float* bias = (const float*)d_in[2];
    float* out = (float*)d_out;
    float* ws  = (float*)d_ws;

    unsigned short* Xhi = (unsigned short*)(ws + OFF_XHI);
    unsigned short* Xlo = (unsigned short*)(ws + OFF_XLO);
    unsigned short* Whi = (unsigned short*)(ws + OFF_WHI);
    unsigned short* Wlo = (unsigned short*)(ws + OFF_WLO);
    float* aggA = ws + OFF_AGGA;
    float* aggB = ws + OFF_AGGB;
    float* pref = ws + OFF_PREF;
    int*   flags = (int*)(ws + OFF_FLAG);

    convert_kernel<<<4104, 256, 0, stream>>>(W, x, Whi, Wlo, Xhi, Xlo, flags);
    gemm_mfma_kernel<<<(NN / 128) * (O4 / 128), 512, 0, stream>>>(
        Xhi, Xlo, Whi, Wlo, bias, out, aggA, aggB, pref, flags);
}

// Round 6
// 240.228 us; speedup vs baseline: 1.4495x; 1.4495x over previous
//
#include <hip/hip_runtime.h>
#include <hip/hip_fp16.h>

#define B_   8
#define CIN  256
#define T_   4096
#define TP   4097    // padded T (row 0 = zeros, row t+1 = x[t])
#define CO   256
#define O4   1024
#define NN   32768   // B_*T_
#define NCH  128     // chunks along T
#define CL   32      // chunk length

// ws layout (float offsets)
#define OFF_XHI  0           // ushort [8][4097][256]
#define OFF_XLO  4195328
#define OFF_WHI  8390656     // ushort [1024][512]
#define OFF_WLO  8652800
#define OFF_F16  8914944     // ushort(f16) [8][4096][256]
#define OFF_IZ16 13109248
#define OFF_O16  17303552
#define OFF_A    21497856    // float [8][128][256]
#define OFF_B    21760000

typedef __attribute__((ext_vector_type(8))) short short8;
typedef __attribute__((ext_vector_type(4))) float floatx4;

__device__ __forceinline__ float fsig(float x)  { return 1.0f / (1.0f + __expf(-x)); }
__device__ __forceinline__ float ftanh(float x) { return 2.0f / (1.0f + __expf(-2.0f * x)) - 1.0f; }

__device__ __forceinline__ unsigned short bf16_rne(float v) {
    unsigned u = __float_as_uint(v);
    unsigned r = (u + 0x7fffu + ((u >> 16) & 1u)) >> 16;
    return (unsigned short)r;
}
__device__ __forceinline__ void split_bf16(float v, unsigned short& hi, unsigned short& lo) {
    hi = bf16_rne(v);
    float hf = __uint_as_float(((unsigned)hi) << 16);
    lo = bf16_rne(v - hf);
}

// async 16B/lane global->LDS DMA; lds base must be wave-uniform (dest = base + lane*16)
__device__ __forceinline__ void glds16(const unsigned short* g, unsigned short* l) {
    __builtin_amdgcn_global_load_lds(
        (const __attribute__((address_space(1))) unsigned*)g,
        (__attribute__((address_space(3))) unsigned*)l, 16, 0, 0);
}

// merged converts: bid<2048 -> W repack/split; bid>=2048 -> X transpose/split.
// W[o=g*256+c][i][j] -> Wa[r=c*4+g][k=j*256+i].  x[b][c][t] -> Xpad[b][t+1][c].
__global__ void convert_kernel(const float* __restrict__ W,
                               const float* __restrict__ x,
                               unsigned short* __restrict__ Whi,
                               unsigned short* __restrict__ Wlo,
                               unsigned short* __restrict__ Xhi,
                               unsigned short* __restrict__ Xlo) {
    __shared__ float tile[64][69];      // 69 mod 32 = 5 -> conflict-free both phases
    const int bid = blockIdx.x;
    const int tid = threadIdx.x;
    if (bid < 2048) {
        int e = bid * 256 + tid;        // 1024*512 elements
        int r = e >> 9, k = e & 511;
        int g = r & 3, c = r >> 2;
        int j = k >> 8, i = k & 255;
        float v = W[((size_t)((g << 8) + c)) * 512 + i * 2 + j];
        unsigned short hi, lo;
        split_bf16(v, hi, lo);
        Whi[e] = hi;
        Wlo[e] = lo;
        return;
    }
    const int b2 = bid - 2048;
    const int t0 = (b2 & 63) * 64;
    const int c0 = ((b2 >> 6) & 3) * 64;
    const int b  = b2 >> 8;

    {   // read: float4 along t, 16 rows per pass
        int j4 = (tid & 15) * 4, r16 = tid >> 4;
#pragma unroll
        for (int p = 0; p < 4; p++) {
            int i = p * 16 + r16;
            float4 v = *(const float4*)&x[((size_t)(b * 256 + c0 + i)) * T_ + t0 + j4];
            tile[i][j4] = v.x; tile[i][j4 + 1] = v.y;
            tile[i][j4 + 2] = v.z; tile[i][j4 + 3] = v.w;
        }
    }
    if (t0 == 0 && tid < 64) {   // zero pad row (x[-1] = 0)
        size_t z = (size_t)b * TP * 256 + c0 + tid;
        Xhi[z] = 0; Xlo[z] = 0;
    }
    __syncthreads();
    {   // write: 4 consecutive channels per thread, packed uint2 (8B) stores
        const int cslot = tid & 15, trow = tid >> 4;
#pragma unroll
        for (int p = 0; p < 4; p++) {
            int t = p * 16 + trow;
            unsigned hi0, hi1, lo0, lo1;
            {
                unsigned short h, l;
                split_bf16(tile[cslot * 4 + 0][t], h, l);
                hi0 = h; lo0 = l;
                split_bf16(tile[cslot * 4 + 1][t], h, l);
                hi0 |= ((unsigned)h) << 16; lo0 |= ((unsigned)l) << 16;
                split_bf16(tile[cslot * 4 + 2][t], h, l);
                hi1 = h; lo1 = l;
                split_bf16(tile[cslot * 4 + 3][t], h, l);
                hi1 |= ((unsigned)h) << 16; lo1 |= ((unsigned)l) << 16;
            }
            size_t idx = ((size_t)b * TP + t0 + t + 1) * 256 + c0 + cslot * 4;
            uint2 ph; ph.x = hi0; ph.y = hi1;
            uint2 pl; pl.x = lo0; pl.y = lo1;
            *(uint2*)&Xhi[idx] = ph;
            *(uint2*)&Xlo[idx] = pl;
        }
    }
}

// C[r=1024][n=32768] = Wa · Xb^T, split-bf16 MFMA (3 products).
// Round 6 = round 4 (128x128, BK=32, 2 blocks/CU, 3-phase counted vmcnt)
// + k-slice-major LDS plane layout: plane = [8 wave-chunks][4 kslices][16
// rows][16B]. Staging SOURCE lane remap (lrow=lane&15, lcol=(lane>>4)*8)
// with UNCHANGED linear dest => writer/reader bijection preserved; fragment
// reads become one contiguous 1KiB stream per ds_read_b128 set (A/B row
// bases are 16-aligned so the chunk index is lane-uniform) — eliminates the
// deterministic 8-way bank conflict of row-major (row-stride 64B put 8 of
// each 16-lane phase group on the same 4 banks; 12.98M conflict cycles).
// LDS planes (ushort idx): AH+0, AL+4096, BH+8192, BL+12288; dbuf +16384.
__launch_bounds__(512, 4)
__global__ void gemm_mfma_kernel(const unsigned short* __restrict__ Xhi,
                                 const unsigned short* __restrict__ Xlo,
                                 const unsigned short* __restrict__ Whi,
                                 const unsigned short* __restrict__ Wlo,
                                 const float* __restrict__ bias,
                                 __half* __restrict__ fw,
                                 __half* __restrict__ izw,
                                 __half* __restrict__ ow,
                                 float* __restrict__ Aw,
                                 float* __restrict__ Bw)
{
    __shared__ unsigned short smem_us[32768];   // 64 KiB

    const int tid  = threadIdx.x;
    const int wave = tid >> 6, lane = tid & 63;
    const int q = lane >> 4, mr = lane & 15;
    const int wm = wave >> 2, wn = wave & 3;     // 2 x 4 wave grid (M x N)

    // grid: 2048 = 8 xcd x (32 n-tiles x 8 r, r fastest -> X-tile L2-resident)
    const int bid   = blockIdx.x;
    const int xcd   = bid & 7;
    const int idx   = bid >> 3;                  // 0..255
    const int n_blk = xcd * 32 + (idx >> 3);     // 0..255
    const int r_blk = idx & 7;                   // 0..7
    const int r0 = r_blk * 128;
    const int n0 = n_blk * 128;
    const int bb = n0 >> 12;
    const int t0 = n0 & (T_ - 1);

    // staging: wave w stages rows w*16..w*16+15; lane carries (row=lane&15,
    // kslice=lane>>4) so the linear LDS dest realizes k-slice-major layout
    const int lrow = lane & 15;            // row within wave-chunk
    const int lcol = (lane >> 4) * 8;      // k-slice ushort offset in row
    const size_t wAoff = (size_t)(r0 + wave * 16 + lrow) * 512 + lcol;
    const unsigned short* pWh = Whi + wAoff;
    const unsigned short* pWl = Wlo + wAoff;
    const size_t xBoff = ((size_t)bb * TP + t0 + wave * 16 + lrow) * 256 + lcol;
    const unsigned short* pXh = Xhi + xBoff;
    const unsigned short* pXl = Xlo + xBoff;

    // fragment read bases (ushort offsets within one plane, k-slice-major):
    // elem(row,q') = (row>>4)*512 + q'*128 + (row&15)*8
    const int aoffb = wm * 2048 + q * 128 + mr * 8;   // + v*512
    const int boffb = wn * 1024 + q * 128 + mr * 8;   // + u*512
    const int wst = wave * 512;                  // wave staging offset in plane

    floatx4 acc[4][2];
#pragma unroll
    for (int v = 0; v < 4; v++)
#pragma unroll
        for (int u = 0; u < 2; u++) acc[v][u] = (floatx4){0.f, 0.f, 0.f, 0.f};

    // prologue: stage K-step 0 into buffer 0, order AH,BH,BL,AL (oldest first)
    glds16(pWh, smem_us + wst);
    glds16(pXh, smem_us + 8192 + wst);
    glds16(pXl, smem_us + 12288 + wst);
    glds16(pWl, smem_us + 4096 + wst);
    asm volatile("s_waitcnt vmcnt(2)" ::: "memory");   // AH,BH landed; BL,AL in flight
    __builtin_amdgcn_s_barrier();
    __builtin_amdgcn_sched_barrier(0);

#pragma unroll 2
    for (int i = 0; i < 16; ++i) {
        const int cur = i & 1, nxt = cur ^ 1;
        const unsigned kk = (unsigned)(((i + 1) & 15) * 32);   // wrap keeps counts uniform
        const unsigned short* AHc = smem_us + cur * 16384;
        const unsigned short* ALc = AHc + 4096;
        const unsigned short* BHc = AHc + 8192;
        const unsigned short* BLc = AHc + 12288;
        unsigned short* dAH = smem_us + nxt * 16384 + wst;
        unsigned short* dAL = dAH + 4096;
        unsigned short* dBH = dAH + 8192;
        unsigned short* dBL = dAH + 12288;

        short8 ah[4], bh[2];

        // ---------- P0: hi*hi ----------
#pragma unroll
        for (int v = 0; v < 4; ++v) ah[v] = *(const short8*)(AHc + aoffb + v * 512);
#pragma unroll
        for (int u = 0; u < 2; ++u) bh[u] = *(const short8*)(BHc + boffb + u * 512);
        glds16(pWh + kk, dAH);
        glds16(pXh + kk, dBH);
        asm volatile("s_waitcnt lgkmcnt(0)" ::: "memory");
        __builtin_amdgcn_sched_barrier(0);
        __builtin_amdgcn_s_setprio(1);
#pragma unroll
        for (int v = 0; v < 4; ++v)
#pragma unroll
            for (int u = 0; u < 2; ++u)
                acc[v][u] = __builtin_amdgcn_mfma_f32_16x16x32_bf16(ah[v], bh[u], acc[v][u], 0, 0, 0);
        __builtin_amdgcn_s_setprio(0);
        asm volatile("s_waitcnt vmcnt(3)" ::: "memory");   // BL[cur] landed
        __builtin_amdgcn_s_barrier();
        __builtin_amdgcn_sched_barrier(0);

        // ---------- P1: hi*lo ----------
        {
            short8 bl[2];
#pragma unroll
            for (int u = 0; u < 2; ++u) bl[u] = *(const short8*)(BLc + boffb + u * 512);
            glds16(pXl + kk, dBL);
            asm volatile("s_waitcnt lgkmcnt(0)" ::: "memory");
            __builtin_amdgcn_sched_barrier(0);
            __builtin_amdgcn_s_setprio(1);
#pragma unroll
            for (int v = 0; v < 4; ++v)
#pragma unroll
                for (int u = 0; u < 2; ++u)
                    acc[v][u] = __builtin_amdgcn_mfma_f32_16x16x32_bf16(ah[v], bl[u], acc[v][u], 0, 0, 0);
            __builtin_amdgcn_s_setprio(0);
        }
        asm volatile("s_waitcnt vmcnt(3)" ::: "memory");   // AL[cur] landed
        __builtin_amdgcn_s_barrier();
        __builtin_amdgcn_sched_barrier(0);

        // ---------- P2: lo*hi ----------
        {
            short8 al[4];
#pragma unroll
            for (int v = 0; v < 4; ++v) al[v] = *(const short8*)(ALc + aoffb + v * 512);
            glds16(pWl + kk, dAL);
            asm volatile("s_waitcnt lgkmcnt(0)" ::: "memory");
            __builtin_amdgcn_sched_barrier(0);
            __builtin_amdgcn_s_setprio(1);
#pragma unroll
            for (int v = 0; v < 4; ++v)
#pragma unroll
                for (int u = 0; u < 2; ++u)
                    acc[v][u] = __builtin_amdgcn_mfma_f32_16x16x32_bf16(al[v], bh[u], acc[v][u], 0, 0, 0);
            __builtin_amdgcn_s_setprio(0);
        }
        asm volatile("s_waitcnt vmcnt(2)" ::: "memory");   // AH,BH[nxt] landed
        __builtin_amdgcn_s_barrier();
        __builtin_amdgcn_sched_barrier(0);
    }

    // ---------- epilogue ----------
    asm volatile("s_waitcnt vmcnt(0)" ::: "memory");   // drain wrap-staging junk DMAs
    __syncthreads();                     // LDS reused below
    __half* epf = (__half*)smem_us;      // [128][36] f16, 72B rows (conflict-free t-phase)
    __half* epz = epf + 128 * 36;
    __half* epo = epz + 128 * 36;        // total 27,648 B < 64 KiB
    const int ch_base = r0 >> 2;         // 32 channels per block

#pragma unroll
    for (int v = 0; v < 4; ++v) {
        const int cl = wm * 16 + v * 4 + q;          // local channel 0..31
        const int ch = ch_base + cl;
        const float bz  = bias[ch];
        const float bf_ = bias[256 + ch];
        const float bo  = bias[512 + ch];
        const float bi  = bias[768 + ch];
#pragma unroll
        for (int u = 0; u < 2; ++u) {
            const int t_l = wn * 32 + u * 16 + mr;   // local t 0..127
            float zv = ftanh(acc[v][u][0] + bz);
            float fv = fsig(acc[v][u][1] + bf_);
            float ov = fsig(acc[v][u][2] + bo);
            float iv = fsig(acc[v][u][3] + bi);
            const int off = t_l * 36 + cl;
            epf[off] = __float2half(fv);             // same f16 rounding as before
            epz[off] = __float2half(iv * zv);
            epo[off] = __float2half(ov);
        }
    }
    __syncthreads();

    // coalesced f16 stores: 4 threads per t-row, 8 channels (16B) each
    {
        const int t_r = tid >> 2;                    // 0..127
        const int c8 = (tid & 3) << 3;               // 0,8,16,24
        const size_t gbase = ((size_t)bb * T_ + t0 + t_r) * 256 + ch_base + c8;
        const int lb = t_r * 36 + c8;                // 8B-aligned
        union { uint2 u2[2]; uint4 u4; } pk;
        pk.u2[0] = *(const uint2*)&epf[lb];
        pk.u2[1] = *(const uint2*)&epf[lb + 4];
        *(uint4*)&fw[gbase] = pk.u4;
        pk.u2[0] = *(const uint2*)&epz[lb];
        pk.u2[1] = *(const uint2*)&epz[lb + 4];
        *(uint4*)&izw[gbase] = pk.u4;
        pk.u2[0] = *(const uint2*)&epo[lb];
        pk.u2[1] = *(const uint2*)&epo[lb + 4];
        *(uint4*)&ow[gbase] = pk.u4;
    }

    // fused scan phase 1: per-chunk (A = prod f, B = affine end); 4 chunks x 32 ch
    if (tid < 128) {
        const int chunk = tid >> 5;                  // 0..3
        const int c = tid & 31;
        float A = 1.0f, Bv = 0.0f;
        const int base = (chunk * 32) * 36 + c;
#pragma unroll 4
        for (int j = 0; j < 32; ++j) {
            float f  = __half2float(epf[base + j * 36]);
            float iz = __half2float(epz[base + j * 36]);
            Bv = fmaf(f, Bv, iz);
            A *= f;
        }
        const int chunk_abs = (t0 >> 5) + chunk;
        const size_t aidx = ((size_t)bb * NCH + chunk_abs) * 256 + ch_base + c;
        Aw[aidx] = A;
        Bw[aidx] = Bv;
    }
}

// Phase 3 (merged with old phase 2): each block computes its own carry from
// the chunk summaries (predicated 16-wide batched loads; Aw/Bw are L2-hot
// 256KB), then replays the recurrence and writes out[b][c][t] transposed.
__global__ void scan_phase3(const __half* __restrict__ fw, const __half* __restrict__ izw,
                            const __half* __restrict__ ow,
                            const float* __restrict__ Aw, const float* __restrict__ Bw,
                            float* __restrict__ out)
{
    __shared__ float hbuf[CL][257];
    __shared__ float carry_s[256];
    int b = blockIdx.y, ch = blockIdx.x;
    int tid = threadIdx.x;

    {   // carry over chunks 0..ch-1 for channel tid (exclusive scan, batched)
        const int c = tid;
        float carry = 0.0f;
        for (int g = 0; g < 8; ++g) {
            if (g * 16 >= ch) break;
            float Ar[16], Br[16];
#pragma unroll
            for (int j = 0; j < 16; ++j) {
                int jj = g * 16 + j;
                bool ok = jj < ch;
                size_t idx2 = ((size_t)(b * NCH + (ok ? jj : 0))) * CO + c;
                Ar[j] = ok ? Aw[idx2] : 1.0f;
                Br[j] = ok ? Bw[idx2] : 0.0f;
            }
#pragma unroll
            for (int j = 0; j < 16; ++j) carry = fmaf(Ar[j], carry, Br[j]);
        }
        carry_s[c] = carry;
    }
    __syncthreads();

    if (tid < 128) {
        const int c2 = tid * 2;
        float cs0 = carry_s[c2];
        float cs1 = carry_s[c2 + 1];
        size_t base = ((size_t)(b * T_ + ch * CL)) * CO + c2;
#pragma unroll 4
        for (int tt = 0; tt < CL; tt++) {
            __half2 f2  = *(const __half2*)&fw [base + (size_t)tt * CO];
            __half2 iz2 = *(const __half2*)&izw[base + (size_t)tt * CO];
            __half2 o2  = *(const __half2*)&ow [base + (size_t)tt * CO];
            float2 f  = __half22float2(f2);
            float2 iz = __half22float2(iz2);
            float2 o  = __half22float2(o2);
            cs0 = fmaf(f.x, cs0, iz.x);
            cs1 = fmaf(f.y, cs1, iz.y);
            hbuf[tt][c2]     = o.x * cs0;
            hbuf[tt][c2 + 1] = o.y * cs1;
        }
    }
    __syncthreads();
    int tt = threadIdx.x & 31;
    int cr = threadIdx.x >> 5;
#pragma unroll
    for (int w = 0; w < 32; w++) {
        int cc = cr + w * 8;
        out[((size_t)(b * CO + cc)) * T_ + ch * CL + tt] = hbuf[tt][cc];
    }
}

extern "C" void kernel_launch(void* const* d_in, const int* in_sizes, int n_in,
                              void* d_out, int out_size, void* d_ws, size_t ws_size,
                              hipStream_t stream) {
    const float* x    = (const float*)d_in[0];
    const float* W    = (const float*)d_in[1];
    const float* bias = (const float*)d_in[2];
    float* out = (float*)d_out;
    float* ws  = (float*)d_ws;

    unsigned short* Xhi = (unsigned short*)(ws + OFF_XHI);
    unsigned short* Xlo = (unsigned short*)(ws + OFF_XLO);
    unsigned short* Whi = (unsigned short*)(ws + OFF_WHI);
    unsigned short* Wlo = (unsigned short*)(ws + OFF_WLO);
    __half* fw  = (__half*)(ws + OFF_F16);
    __half* izw = (__half*)(ws + OFF_IZ16);
    __half* ow  = (__half*)(ws + OFF_O16);
    float* Aw  = ws + OFF_A;
    float* Bw  = ws + OFF_B;

    convert_kernel<<<4096, 256, 0, stream>>>(W, x, Whi, Wlo, Xhi, Xlo);
    gemm_mfma_kernel<<<(NN / 128) * (O4 / 128), 512, 0, stream>>>(
        Xhi, Xlo, Whi, Wlo, bias, fw, izw, ow, Aw, Bw);
    scan_phase3<<<dim3(NCH, B_), CO, 0, stream>>>(fw, izw, ow, Aw, Bw, out);
}

// Round 7
// 210.162 us; speedup vs baseline: 1.6569x; 1.1431x over previous
//
#include <hip/hip_runtime.h>
#include <hip/hip_fp16.h>

#define B_   8
#define CIN  256
#define T_   4096
#define TP   4097    // padded T (row 0 = zeros, row t+1 = x[t])
#define CO   256
#define O4   1024
#define NN   32768   // B_*T_
#define NCH  128     // chunks along T
#define CL   32      // chunk length

// ws layout (float offsets)
#define OFF_XHI  0           // ushort [8][4097][256]
#define OFF_XLO  4195328
#define OFF_WHI  8390656     // ushort [1024][512]
#define OFF_WLO  8652800
#define OFF_F16  8914944     // ushort(f16) [8][4096][256]
#define OFF_IZ16 13109248
#define OFF_O16  17303552
#define OFF_A    21497856    // float [8][128][256]
#define OFF_B    21760000

typedef __attribute__((ext_vector_type(8))) short short8;
typedef __attribute__((ext_vector_type(4))) float floatx4;

__device__ __forceinline__ float fsig(float x)  { return 1.0f / (1.0f + __expf(-x)); }
__device__ __forceinline__ float ftanh(float x) { return 2.0f / (1.0f + __expf(-2.0f * x)) - 1.0f; }

__device__ __forceinline__ unsigned short bf16_rne(float v) {
    unsigned u = __float_as_uint(v);
    unsigned r = (u + 0x7fffu + ((u >> 16) & 1u)) >> 16;
    return (unsigned short)r;
}
__device__ __forceinline__ void split_bf16(float v, unsigned short& hi, unsigned short& lo) {
    hi = bf16_rne(v);
    float hf = __uint_as_float(((unsigned)hi) << 16);
    lo = bf16_rne(v - hf);
}

// async 16B/lane global->LDS DMA; lds base must be wave-uniform (dest = base + lane*16)
__device__ __forceinline__ void glds16(const unsigned short* g, unsigned short* l) {
    __builtin_amdgcn_global_load_lds(
        (const __attribute__((address_space(1))) unsigned*)g,
        (__attribute__((address_space(3))) unsigned*)l, 16, 0, 0);
}

// merged converts: bid<2048 -> W repack/split; bid>=2048 -> X transpose/split.
// W[o=g*256+c][i][j] -> Wa[r=c*4+g][k=j*256+i].  x[b][c][t] -> Xpad[b][t+1][c].
__global__ void convert_kernel(const float* __restrict__ W,
                               const float* __restrict__ x,
                               unsigned short* __restrict__ Whi,
                               unsigned short* __restrict__ Wlo,
                               unsigned short* __restrict__ Xhi,
                               unsigned short* __restrict__ Xlo) {
    __shared__ float tile[64][69];      // 69 mod 32 = 5 -> conflict-free both phases
    const int bid = blockIdx.x;
    const int tid = threadIdx.x;
    if (bid < 2048) {
        int e = bid * 256 + tid;        // 1024*512 elements
        int r = e >> 9, k = e & 511;
        int g = r & 3, c = r >> 2;
        int j = k >> 8, i = k & 255;
        float v = W[((size_t)((g << 8) + c)) * 512 + i * 2 + j];
        unsigned short hi, lo;
        split_bf16(v, hi, lo);
        Whi[e] = hi;
        Wlo[e] = lo;
        return;
    }
    const int b2 = bid - 2048;
    const int t0 = (b2 & 63) * 64;
    const int c0 = ((b2 >> 6) & 3) * 64;
    const int b  = b2 >> 8;

    {   // read: float4 along t, 16 rows per pass
        int j4 = (tid & 15) * 4, r16 = tid >> 4;
#pragma unroll
        for (int p = 0; p < 4; p++) {
            int i = p * 16 + r16;
            float4 v = *(const float4*)&x[((size_t)(b * 256 + c0 + i)) * T_ + t0 + j4];
            tile[i][j4] = v.x; tile[i][j4 + 1] = v.y;
            tile[i][j4 + 2] = v.z; tile[i][j4 + 3] = v.w;
        }
    }
    if (t0 == 0 && tid < 64) {   // zero pad row (x[-1] = 0)
        size_t z = (size_t)b * TP * 256 + c0 + tid;
        Xhi[z] = 0; Xlo[z] = 0;
    }
    __syncthreads();
    {   // write: 4 consecutive channels per thread, packed uint2 (8B) stores
        const int cslot = tid & 15, trow = tid >> 4;
#pragma unroll
        for (int p = 0; p < 4; p++) {
            int t = p * 16 + trow;
            unsigned hi0, hi1, lo0, lo1;
            {
                unsigned short h, l;
                split_bf16(tile[cslot * 4 + 0][t], h, l);
                hi0 = h; lo0 = l;
                split_bf16(tile[cslot * 4 + 1][t], h, l);
                hi0 |= ((unsigned)h) << 16; lo0 |= ((unsigned)l) << 16;
                split_bf16(tile[cslot * 4 + 2][t], h, l);
                hi1 = h; lo1 = l;
                split_bf16(tile[cslot * 4 + 3][t], h, l);
                hi1 |= ((unsigned)h) << 16; lo1 |= ((unsigned)l) << 16;
            }
            size_t idx = ((size_t)b * TP + t0 + t + 1) * 256 + c0 + cslot * 4;
            uint2 ph; ph.x = hi0; ph.y = hi1;
            uint2 pl; pl.x = lo0; pl.y = lo1;
            *(uint2*)&Xhi[idx] = ph;
            *(uint2*)&Xlo[idx] = pl;
        }
    }
}

// C[r=1024][n=32768] = Wa · Xb^T, split-bf16 MFMA (3 products).
// Round 7 = round-4 structure (128x128, BK=32, 2 blocks/CU, 3-phase counted
// vmcnt, coalesced 64B/4-lane staging) + BOTH-SIDES XOR SWIZZLE (T2/m201):
//   writer: slice index s=lane&3 fetches global slice s ^ ((lrow>>1)&3)
//           (permutes 16B chunks WITHIN each row's contiguous 64B — global
//           coalescing preserved, unlike round 6's k-slice remap which
//           scattered lanes at 512B stride and broke the DMA: 155µs);
//   reader: q*8 -> (q ^ ((mr>>1)&3))*8. Bijective (row bases 16-aligned =>
//           (row>>1)&3 == (mr>>1)&3 on both sides).
// Bank check: read quad = (4*(mr&1) + (q^((mr>>1)&3))) mod 8 — all 8 quads
// twice over mr=0..15 => 2 lanes/quad = free (m136). Round 4's layout had
// 8 lanes/quad => 12.98M conflict cycles; round 6 proved removal (393K).
// LDS planes (ushort idx): AH+0, AL+4096, BH+8192, BL+12288; dbuf +16384.
__launch_bounds__(512, 4)
__global__ void gemm_mfma_kernel(const unsigned short* __restrict__ Xhi,
                                 const unsigned short* __restrict__ Xlo,
                                 const unsigned short* __restrict__ Whi,
                                 const unsigned short* __restrict__ Wlo,
                                 const float* __restrict__ bias,
                                 __half* __restrict__ fw,
                                 __half* __restrict__ izw,
                                 __half* __restrict__ ow,
                                 float* __restrict__ Aw,
                                 float* __restrict__ Bw)
{
    __shared__ unsigned short smem_us[32768];   // 64 KiB

    const int tid  = threadIdx.x;
    const int wave = tid >> 6, lane = tid & 63;
    const int q = lane >> 4, mr = lane & 15;
    const int wm = wave >> 2, wn = wave & 3;     // 2 x 4 wave grid (M x N)

    // grid: 2048 = 8 xcd x (32 n-tiles x 8 r, r fastest -> X-tile L2-resident)
    const int bid   = blockIdx.x;
    const int xcd   = bid & 7;
    const int idx   = bid >> 3;                  // 0..255
    const int n_blk = xcd * 32 + (idx >> 3);     // 0..255
    const int r_blk = idx & 7;                   // 0..7
    const int r0 = r_blk * 128;
    const int n0 = n_blk * 128;
    const int bb = n0 >> 12;
    const int t0 = n0 & (T_ - 1);

    // staging: wave w stages rows w*16..w*16+15 of each plane; 1 DMA per plane.
    // XOR-swizzled source slice (within the row's contiguous 64B window).
    const int lrow = lane >> 2;                              // 0..15
    const int lcol = (((lane & 3) ^ ((lrow >> 1) & 3)) * 8); // swizzled ushort offset
    const size_t wAoff = (size_t)(r0 + wave * 16 + lrow) * 512 + lcol;
    const unsigned short* pWh = Whi + wAoff;
    const unsigned short* pWl = Wlo + wAoff;
    const size_t xBoff = ((size_t)bb * TP + t0 + wave * 16 + lrow) * 256 + lcol;
    const unsigned short* pXh = Xhi + xBoff;
    const unsigned short* pXl = Xlo + xBoff;

    // fragment read bases (ushort offsets within one plane, swizzled slice)
    const int swz = (q ^ ((mr >> 1) & 3)) * 8;
    const int aoffb = (wm * 64 + mr) * 32 + swz;   // + v*512
    const int boffb = (wn * 32 + mr) * 32 + swz;   // + u*512
    const int wst = wave * 512;                  // wave staging offset in plane

    floatx4 acc[4][2];
#pragma unroll
    for (int v = 0; v < 4; v++)
#pragma unroll
        for (int u = 0; u < 2; u++) acc[v][u] = (floatx4){0.f, 0.f, 0.f, 0.f};

    // prologue: stage K-step 0 into buffer 0, order AH,BH,BL,AL (oldest first)
    glds16(pWh, smem_us + wst);
    glds16(pXh, smem_us + 8192 + wst);
    glds16(pXl, smem_us + 12288 + wst);
    glds16(pWl, smem_us + 4096 + wst);
    asm volatile("s_waitcnt vmcnt(2)" ::: "memory");   // AH,BH landed; BL,AL in flight
    __builtin_amdgcn_s_barrier();
    __builtin_amdgcn_sched_barrier(0);

#pragma unroll 2
    for (int i = 0; i < 16; ++i) {
        const int cur = i & 1, nxt = cur ^ 1;
        const unsigned kk = (unsigned)(((i + 1) & 15) * 32);   // wrap keeps counts uniform
        const unsigned short* AHc = smem_us + cur * 16384;
        const unsigned short* ALc = AHc + 4096;
        const unsigned short* BHc = AHc + 8192;
        const unsigned short* BLc = AHc + 12288;
        unsigned short* dAH = smem_us + nxt * 16384 + wst;
        unsigned short* dAL = dAH + 4096;
        unsigned short* dBH = dAH + 8192;
        unsigned short* dBL = dAH + 12288;

        short8 ah[4], bh[2];

        // ---------- P0: hi*hi ----------
#pragma unroll
        for (int v = 0; v < 4; ++v) ah[v] = *(const short8*)(AHc + aoffb + v * 512);
#pragma unroll
        for (int u = 0; u < 2; ++u) bh[u] = *(const short8*)(BHc + boffb + u * 512);
        glds16(pWh + kk, dAH);
        glds16(pXh + kk, dBH);
        asm volatile("s_waitcnt lgkmcnt(0)" ::: "memory");
        __builtin_amdgcn_sched_barrier(0);
        __builtin_amdgcn_s_setprio(1);
#pragma unroll
        for (int v = 0; v < 4; ++v)
#pragma unroll
            for (int u = 0; u < 2; ++u)
                acc[v][u] = __builtin_amdgcn_mfma_f32_16x16x32_bf16(ah[v], bh[u], acc[v][u], 0, 0, 0);
        __builtin_amdgcn_s_setprio(0);
        asm volatile("s_waitcnt vmcnt(3)" ::: "memory");   // BL[cur] landed
        __builtin_amdgcn_s_barrier();
        __builtin_amdgcn_sched_barrier(0);

        // ---------- P1: hi*lo ----------
        {
            short8 bl[2];
#pragma unroll
            for (int u = 0; u < 2; ++u) bl[u] = *(const short8*)(BLc + boffb + u * 512);
            glds16(pXl + kk, dBL);
            asm volatile("s_waitcnt lgkmcnt(0)" ::: "memory");
            __builtin_amdgcn_sched_barrier(0);
            __builtin_amdgcn_s_setprio(1);
#pragma unroll
            for (int v = 0; v < 4; ++v)
#pragma unroll
                for (int u = 0; u < 2; ++u)
                    acc[v][u] = __builtin_amdgcn_mfma_f32_16x16x32_bf16(ah[v], bl[u], acc[v][u], 0, 0, 0);
            __builtin_amdgcn_s_setprio(0);
        }
        asm volatile("s_waitcnt vmcnt(3)" ::: "memory");   // AL[cur] landed
        __builtin_amdgcn_s_barrier();
        __builtin_amdgcn_sched_barrier(0);

        // ---------- P2: lo*hi ----------
        {
            short8 al[4];
#pragma unroll
            for (int v = 0; v < 4; ++v) al[v] = *(const short8*)(ALc + aoffb + v * 512);
            glds16(pWl + kk, dAL);
            asm volatile("s_waitcnt lgkmcnt(0)" ::: "memory");
            __builtin_amdgcn_sched_barrier(0);
            __builtin_amdgcn_s_setprio(1);
#pragma unroll
            for (int v = 0; v < 4; ++v)
#pragma unroll
                for (int u = 0; u < 2; ++u)
                    acc[v][u] = __builtin_amdgcn_mfma_f32_16x16x32_bf16(al[v], bh[u], acc[v][u], 0, 0, 0);
            __builtin_amdgcn_s_setprio(0);
        }
        asm volatile("s_waitcnt vmcnt(2)" ::: "memory");   // AH,BH[nxt] landed
        __builtin_amdgcn_s_barrier();
        __builtin_amdgcn_sched_barrier(0);
    }

    // ---------- epilogue ----------
    asm volatile("s_waitcnt vmcnt(0)" ::: "memory");   // drain wrap-staging junk DMAs
    __syncthreads();                     // LDS reused below
    __half* epf = (__half*)smem_us;      // [128][36] f16, 72B rows (conflict-free t-phase)
    __half* epz = epf + 128 * 36;
    __half* epo = epz + 128 * 36;        // total 27,648 B < 64 KiB
    const int ch_base = r0 >> 2;         // 32 channels per block

#pragma unroll
    for (int v = 0; v < 4; ++v) {
        const int cl = wm * 16 + v * 4 + q;          // local channel 0..31
        const int ch = ch_base + cl;
        const float bz  = bias[ch];
        const float bf_ = bias[256 + ch];
        const float bo  = bias[512 + ch];
        const float bi  = bias[768 + ch];
#pragma unroll
        for (int u = 0; u < 2; ++u) {
            const int t_l = wn * 32 + u * 16 + mr;   // local t 0..127
            float zv = ftanh(acc[v][u][0] + bz);
            float fv = fsig(acc[v][u][1] + bf_);
            float ov = fsig(acc[v][u][2] + bo);
            float iv = fsig(acc[v][u][3] + bi);
            const int off = t_l * 36 + cl;
            epf[off] = __float2half(fv);             // same f16 rounding as before
            epz[off] = __float2half(iv * zv);
            epo[off] = __float2half(ov);
        }
    }
    __syncthreads();

    // coalesced f16 stores: 4 threads per t-row, 8 channels (16B) each
    {
        const int t_r = tid >> 2;                    // 0..127
        const int c8 = (tid & 3) << 3;               // 0,8,16,24
        const size_t gbase = ((size_t)bb * T_ + t0 + t_r) * 256 + ch_base + c8;
        const int lb = t_r * 36 + c8;                // 8B-aligned
        union { uint2 u2[2]; uint4 u4; } pk;
        pk.u2[0] = *(const uint2*)&epf[lb];
        pk.u2[1] = *(const uint2*)&epf[lb + 4];
        *(uint4*)&fw[gbase] = pk.u4;
        pk.u2[0] = *(const uint2*)&epz[lb];
        pk.u2[1] = *(const uint2*)&epz[lb + 4];
        *(uint4*)&izw[gbase] = pk.u4;
        pk.u2[0] = *(const uint2*)&epo[lb];
        pk.u2[1] = *(const uint2*)&epo[lb + 4];
        *(uint4*)&ow[gbase] = pk.u4;
    }

    // fused scan phase 1: per-chunk (A = prod f, B = affine end); 4 chunks x 32 ch
    if (tid < 128) {
        const int chunk = tid >> 5;                  // 0..3
        const int c = tid & 31;
        float A = 1.0f, Bv = 0.0f;
        const int base = (chunk * 32) * 36 + c;
#pragma unroll 4
        for (int j = 0; j < 32; ++j) {
            float f  = __half2float(epf[base + j * 36]);
            float iz = __half2float(epz[base + j * 36]);
            Bv = fmaf(f, Bv, iz);
            A *= f;
        }
        const int chunk_abs = (t0 >> 5) + chunk;
        const size_t aidx = ((size_t)bb * NCH + chunk_abs) * 256 + ch_base + c;
        Aw[aidx] = A;
        Bw[aidx] = Bv;
    }
}

// Phase 3 (merged with old phase 2): each block computes its own carry from
// the chunk summaries (predicated 16-wide batched loads; Aw/Bw are L2-hot
// 256KB), then replays the recurrence and writes out[b][c][t] transposed.
__global__ void scan_phase3(const __half* __restrict__ fw, const __half* __restrict__ izw,
                            const __half* __restrict__ ow,
                            const float* __restrict__ Aw, const float* __restrict__ Bw,
                            float* __restrict__ out)
{
    __shared__ float hbuf[CL][257];
    __shared__ float carry_s[256];
    int b = blockIdx.y, ch = blockIdx.x;
    int tid = threadIdx.x;

    {   // carry over chunks 0..ch-1 for channel tid (exclusive scan, batched)
        const int c = tid;
        float carry = 0.0f;
        for (int g = 0; g < 8; ++g) {
            if (g * 16 >= ch) break;
            float Ar[16], Br[16];
#pragma unroll
            for (int j = 0; j < 16; ++j) {
                int jj = g * 16 + j;
                bool ok = jj < ch;
                size_t idx2 = ((size_t)(b * NCH + (ok ? jj : 0))) * CO + c;
                Ar[j] = ok ? Aw[idx2] : 1.0f;
                Br[j] = ok ? Bw[idx2] : 0.0f;
            }
#pragma unroll
            for (int j = 0; j < 16; ++j) carry = fmaf(Ar[j], carry, Br[j]);
        }
        carry_s[c] = carry;
    }
    __syncthreads();

    if (tid < 128) {
        const int c2 = tid * 2;
        float cs0 = carry_s[c2];
        float cs1 = carry_s[c2 + 1];
        size_t base = ((size_t)(b * T_ + ch * CL)) * CO + c2;
#pragma unroll 4
        for (int tt = 0; tt < CL; tt++) {
            __half2 f2  = *(const __half2*)&fw [base + (size_t)tt * CO];
            __half2 iz2 = *(const __half2*)&izw[base + (size_t)tt * CO];
            __half2 o2  = *(const __half2*)&ow [base + (size_t)tt * CO];
            float2 f  = __half22float2(f2);
            float2 iz = __half22float2(iz2);
            float2 o  = __half22float2(o2);
            cs0 = fmaf(f.x, cs0, iz.x);
            cs1 = fmaf(f.y, cs1, iz.y);
            hbuf[tt][c2]     = o.x * cs0;
            hbuf[tt][c2 + 1] = o.y * cs1;
        }
    }
    __syncthreads();
    int tt = threadIdx.x & 31;
    int cr = threadIdx.x >> 5;
#pragma unroll
    for (int w = 0; w < 32; w++) {
        int cc = cr + w * 8;
        out[((size_t)(b * CO + cc)) * T_ + ch * CL + tt] = hbuf[tt][cc];
    }
}

extern "C" void kernel_launch(void* const* d_in, const int* in_sizes, int n_in,
                              void* d_out, int out_size, void* d_ws, size_t ws_size,
                              hipStream_t stream) {
    const float* x    = (const float*)d_in[0];
    const float* W    = (const float*)d_in[1];
    const float* bias = (const float*)d_in[2];
    float* out = (float*)d_out;
    float* ws  = (float*)d_ws;

    unsigned short* Xhi = (unsigned short*)(ws + OFF_XHI);
    unsigned short* Xlo = (unsigned short*)(ws + OFF_XLO);
    unsigned short* Whi = (unsigned short*)(ws + OFF_WHI);
    unsigned short* Wlo = (unsigned short*)(ws + OFF_WLO);
    __half* fw  = (__half*)(ws + OFF_F16);
    __half* izw = (__half*)(ws + OFF_IZ16);
    __half* ow  = (__half*)(ws + OFF_O16);
    float* Aw  = ws + OFF_A;
    float* Bw  = ws + OFF_B;

    convert_kernel<<<4096, 256, 0, stream>>>(W, x, Whi, Wlo, Xhi, Xlo);
    gemm_mfma_kernel<<<(NN / 128) * (O4 / 128), 512, 0, stream>>>(
        Xhi, Xlo, Whi, Wlo, bias, fw, izw, ow, Aw, Bw);
    scan_phase3<<<dim3(NCH, B_), CO, 0, stream>>>(fw, izw, ow, Aw, Bw, out);
}